// Round 5
// baseline (112.338 us; speedup 1.0000x reference)
//
#include <hip/hip_runtime.h>

#define NV 30000
#define NB 128
#define NS 512
#define ND 300
#define NC 300
#define CP 304     // padded C (f32 buffers)
#define KP 320     // padded K / BMT row stride
#define EP 304     // E row stride (bf16)
#define MASK_NEG -1e9f
#define SQ_EPS 1e-8f

typedef __attribute__((ext_vector_type(4))) float f32x4;
typedef __attribute__((ext_vector_type(8))) __bf16 bf16x8;

__device__ __forceinline__ unsigned short f2bf(float x){
  unsigned int u = __float_as_uint(x);
  u += 0x7FFFu + ((u >> 16) & 1u);
  return (unsigned short)(u >> 16);
}
__device__ __forceinline__ float bf2f(unsigned short h){
  return __uint_as_float(((unsigned int)h) << 16);
}

__device__ __forceinline__ float bsum512(float v, float* red, int tid){
  red[tid] = v; __syncthreads();
  float s = 0.f;
  if (tid < 64){
    s = red[tid]+red[tid+64]+red[tid+128]+red[tid+192]
      + red[tid+256]+red[tid+320]+red[tid+384]+red[tid+448];
    #pragma unroll
    for (int off = 32; off > 0; off >>= 1) s += __shfl_xor(s, off);
    if (tid == 0) red[0] = s;
  }
  __syncthreads();
  s = red[0];
  __syncthreads();
  return s;
}

__device__ __forceinline__ float bmax512(float v, float* red, int tid){
  red[tid] = v; __syncthreads();
  float s = MASK_NEG;
  if (tid < 64){
    s = red[tid];
    #pragma unroll
    for (int o = 64; o < 512; o += 64) s = fmaxf(s, red[tid+o]);
    #pragma unroll
    for (int off = 32; off > 0; off >>= 1) s = fmaxf(s, __shfl_xor(s, off));
    if (tid == 0) red[0] = s;
  }
  __syncthreads();
  s = red[0];
  __syncthreads();
  return s;
}

// ---------------- KPREP: 0..24 Ws-transpose; 25 bsp+BMT row131+zero rows; 26..153 aspect(b); 154..156 guide(k)
__global__ __launch_bounds__(512) void kprep(
    const float* __restrict__ Ws, const float* __restrict__ Watt,
    const float* __restrict__ Gw, const float* __restrict__ bs,
    const float* __restrict__ gcap, const int* __restrict__ aspect,
    const float* __restrict__ embed, const float* __restrict__ Wa,
    const float* __restrict__ ba,
    unsigned short* __restrict__ wt, float* __restrict__ bsp,
    unsigned short* __restrict__ BMT)
{
  int bid = blockIdx.x, tid = threadIdx.x;
  int lane = tid & 63, w = tid >> 6;
  __shared__ float sh[64*65];
  float* aspL = sh;             // [320]
  float* capL = sh + 320;       // [320]
  float* red  = sh + 640;       // [512]

  if (bid < 25) {
    float (*t)[65] = (float(*)[65])sh;
    int kt = bid / 5, nt = bid - kt*5;
    #pragma unroll
    for (int i = 0; i < 8; i++){
      int idx = i*512 + tid;
      int r = idx >> 6, c = idx & 63;
      int gk = kt*64 + r, gn = nt*64 + c;
      t[r][c] = (gk < ND && gn < NC) ? Ws[gk*NC + gn] : 0.f;
    }
    __syncthreads();
    #pragma unroll
    for (int i = 0; i < 8; i++){
      int idx = i*512 + tid;
      int n = idx >> 6, k = idx & 63;
      wt[(nt*64 + n)*KP + kt*64 + k] = f2bf(t[k][n]);
    }
  } else if (bid == 25) {
    float bv = 0.f;
    if (tid < 320){
      bv = (tid < NC) ? bs[tid] : 0.f;
      bsp[tid] = bv;
      BMT[131*KP + tid] = f2bf(bv);
    }
    // zero BMT rows 132..159
    for (int i = tid; i < 28*KP; i += 512) BMT[132*KP + i] = 0;
  } else if (bid < 154) {
    int b = bid - 26;
    int a = aspect[b];
    if (tid < 320) aspL[tid] = (tid < ND) ? embed[(size_t)a*ND + tid] : 0.f;
    __syncthreads();
    int c = tid;
    float p0=0.f,p1=0.f,p2=0.f,p3=0.f,p4=0.f,p5=0.f;
    if (c < NC){
      for (int d = 0; d < 300; d += 6){
        p0 += Wa[(d+0)*NC + c]*aspL[d+0];
        p1 += Wa[(d+1)*NC + c]*aspL[d+1];
        p2 += Wa[(d+2)*NC + c]*aspL[d+2];
        p3 += Wa[(d+3)*NC + c]*aspL[d+3];
        p4 += Wa[(d+4)*NC + c]*aspL[d+4];
        p5 += Wa[(d+5)*NC + c]*aspL[d+5];
      }
    }
    float z = (c < NC) ? (ba[c] + ((p0+p1)+(p2+p3)+(p4+p5))) : 0.f;
    float sq = bsum512((c < NC) ? z*z : 0.f, red, tid);
    float ssv = (sq/(1.f+sq))/sqrtf(sq + SQ_EPS);
    if (tid < 320) capL[tid] = (c < NC) ? z*ssv : 0.f;
    __syncthreads();
    for (int cc = w; cc < NC; cc += 8){
      const float* wr = Watt + (size_t)cc*NC;
      float acc = 0.f;
      #pragma unroll
      for (int j = 0; j < 5; j++){
        int d = j*64 + lane;
        float wv = (d < ND) ? wr[d] : 0.f;
        acc += wv*capL[d];
      }
      #pragma unroll
      for (int off = 32; off > 0; off >>= 1) acc += __shfl_xor(acc, off);
      if (lane == 0) BMT[(size_t)b*KP + cc] = f2bf(acc);
    }
    if (tid < 20) BMT[(size_t)b*KP + 300 + tid] = 0;
  } else {
    int k = bid - 154;   // 0..2
    if (tid < 320) aspL[tid] = (tid < NC) ? gcap[k*NC + tid] : 0.f;
    __syncthreads();
    float g = (tid < 320) ? aspL[tid] : 0.f;
    float sq = bsum512((tid < NC) ? g*g : 0.f, red, tid);
    float ssv = (sq/(1.f+sq))/sqrtf(sq + SQ_EPS);
    if (tid < 320) capL[tid] = g*ssv;
    __syncthreads();
    for (int cc = w; cc < NC; cc += 8){
      const float* wr = Gw + (size_t)cc*NC;
      float acc = 0.f;
      #pragma unroll
      for (int j = 0; j < 5; j++){
        int d = j*64 + lane;
        float wv = (d < ND) ? wr[d] : 0.f;
        acc += wv*capL[d];
      }
      #pragma unroll
      for (int off = 32; off > 0; off >>= 1) acc += __shfl_xor(acc, off);
      if (lane == 0) BMT[(size_t)(128+k)*KP + cc] = f2bf(acc);
    }
    if (tid < 20) BMT[(size_t)(128+k)*KP + 300 + tid] = 0;
  }
}

// ---------------- K1F: E = embed @ W_s (MFMA) ; then EtT/ETS = [Etile;bs] @ BMT^T ; + e.e
#define BM 64
#define BKT 64
#define LDK 72
#define LDE 328
__global__ __launch_bounds__(512) void k1f(
    const float* __restrict__ embed, const unsigned short* __restrict__ wt,
    const unsigned short* __restrict__ BMT, const float* __restrict__ bsp,
    unsigned short* __restrict__ E, float* __restrict__ EtT,
    float* __restrict__ ETS)
{
  __shared__ unsigned short lds_a[BM*LDK];
  __shared__ unsigned short lds_b[KP*LDK];    // reused as Etile [64][LDE] (41984 B <= 46080)
  __shared__ float e2part[4][BM];
  int tid = threadIdx.x;
  int lane = tid & 63, wid = tid >> 6;
  int bid = blockIdx.x;
  bool special = (bid == (NV + BM - 1)/BM);   // 469
  int rowbase = special ? NV : bid * BM;
  unsigned short* et = lds_b;                 // Etile view

  if (!special){
    int wrow = wid >> 2, wcol = wid & 3;
    f32x4 acc[2][5];
    f32x4 zero = {0.f,0.f,0.f,0.f};
    #pragma unroll
    for (int m = 0; m < 2; m++)
      #pragma unroll
      for (int n = 0; n < 5; n++) acc[m][n] = zero;

    for (int k0 = 0; k0 < KP; k0 += BKT){
      #pragma unroll
      for (int r = 0; r < 2; r++){
        int id = r*512 + tid;                 // < 1024
        int row = id >> 4, k4 = (id & 15) << 2;
        int gk = k0 + k4, grow = rowbase + row;
        float4 v = {0.f,0.f,0.f,0.f};
        if (grow < NV && gk < ND) v = *(const float4*)(embed + (size_t)grow*ND + gk);
        unsigned int lo = (unsigned int)f2bf(v.x) | ((unsigned int)f2bf(v.y) << 16);
        unsigned int hi = (unsigned int)f2bf(v.z) | ((unsigned int)f2bf(v.w) << 16);
        uint2 pk; pk.x = lo; pk.y = hi;
        *(uint2*)(lds_a + row*LDK + k4) = pk;
      }
      #pragma unroll
      for (int r = 0; r < 5; r++){
        int id = r*512 + tid;                 // < 2560
        int n = id >> 3, koff = (id & 7) << 3;
        uint4 v = *(const uint4*)(wt + n*KP + k0 + koff);
        *(uint4*)(lds_b + n*LDK + koff) = v;
      }
      __syncthreads();
      #pragma unroll
      for (int kk = 0; kk < BKT; kk += 32){
        bf16x8 af[2], bfr[5];
        int kidx = kk + (lane >> 4)*8;
        int arow = wrow*32 + (lane & 15);
        int brow = wcol*80 + (lane & 15);
        #pragma unroll
        for (int m = 0; m < 2; m++) af[m] = *(const bf16x8*)(lds_a + (arow + m*16)*LDK + kidx);
        #pragma unroll
        for (int n = 0; n < 5; n++) bfr[n] = *(const bf16x8*)(lds_b + (brow + n*16)*LDK + kidx);
        #pragma unroll
        for (int m = 0; m < 2; m++)
          #pragma unroll
          for (int n = 0; n < 5; n++)
            acc[m][n] = __builtin_amdgcn_mfma_f32_16x16x32_bf16(af[m], bfr[n], acc[m][n], 0, 0, 0);
      }
      __syncthreads();
    }
    // E global write + Etile LDS write + e.e partials
    int colb = wcol*80 + (lane & 15);
    int rowb0 = wrow*32 + ((lane >> 4) << 2);
    #pragma unroll
    for (int m = 0; m < 2; m++)
      #pragma unroll
      for (int n = 0; n < 5; n++)
        #pragma unroll
        for (int j = 0; j < 4; j++){
          int rloc = rowb0 + m*16 + j;
          int row = rowbase + rloc;
          int col = colb + n*16;
          unsigned short h = f2bf(acc[m][n][j]);
          if (row < NV && col < EP) E[(size_t)row*EP + col] = h;
          et[rloc*LDE + col] = h;
        }
    #pragma unroll
    for (int m = 0; m < 2; m++)
      #pragma unroll
      for (int j = 0; j < 4; j++){
        float p = 0.f;
        #pragma unroll
        for (int n = 0; n < 5; n++){ float t = acc[m][n][j]; p += t*t; }
        #pragma unroll
        for (int off = 1; off < 16; off <<= 1) p += __shfl_xor(p, off);
        if ((lane & 15) == 0)
          e2part[wcol][rowb0 + m*16 + j] = p;
      }
  } else {
    // bs row: Etile row 0 = bsp, rest zero
    for (int i = tid; i < 64*LDE; i += 512) et[i] = 0;
    if (tid < 320) et[tid] = f2bf(bsp[tid]);
  }
  __syncthreads();
  if (!special && tid < BM){
    int grow = rowbase + tid;
    if (grow < NV){
      float s = e2part[0][tid] + e2part[1][tid] + e2part[2][tid] + e2part[3][tid];
      ETS[(size_t)grow*8 + 4] = s;
    }
  }
  // ---- 2nd GEMM: [64 x 320] Etile @ BMT[160 x 320]^T
  int wr2 = wid >> 1, wc2 = wid & 1;
  f32x4 acc2[5];
  f32x4 z2 = {0.f,0.f,0.f,0.f};
  #pragma unroll
  for (int n = 0; n < 5; n++) acc2[n] = z2;
  #pragma unroll 2
  for (int kk = 0; kk < KP; kk += 32){
    int kidx = kk + (lane >> 4)*8;
    bf16x8 a2 = *(const bf16x8*)(et + (wr2*16 + (lane & 15))*LDE + kidx);
    #pragma unroll
    for (int n = 0; n < 5; n++){
      bf16x8 b2 = *(const bf16x8*)(BMT + (size_t)(wc2*80 + n*16 + (lane & 15))*KP + kidx);
      acc2[n] = __builtin_amdgcn_mfma_f32_16x16x32_bf16(a2, b2, acc2[n], 0, 0, 0);
    }
  }
  int colb2 = wc2*80 + (lane & 15);
  int rowb2 = rowbase + wr2*16 + ((lane >> 4) << 2);
  int rlim = special ? (NV + 1) : NV;
  #pragma unroll
  for (int n = 0; n < 5; n++)
    #pragma unroll
    for (int j = 0; j < 4; j++){
      int row = rowb2 + j;
      int col = colb2 + n*16;
      if (row < rlim){
        if (col < 128)      EtT[(size_t)row*128 + col] = acc2[n][j];
        else if (col < 132) ETS[(size_t)row*8 + (col - 128)] = acc2[n][j];
      }
    }
}

// ---------------- K45: per-b stats -> softmax -> weighted E-row gather -> out
__global__ __launch_bounds__(512) void k45(
    const int* __restrict__ sentence, const float* __restrict__ alpha,
    const float* __restrict__ scale_p, const unsigned short* __restrict__ E,
    const float* __restrict__ EtT, const float* __restrict__ ETS,
    const float* __restrict__ bsp, float* __restrict__ out)
{
  int b = blockIdx.x, tid = threadIdx.x;
  int lane = tid & 63, w = tid >> 6;
  __shared__ float red[512];
  __shared__ float cfs[NS*3];
  __shared__ int toksh[NS];
  __shared__ float cap8[8][3][CP];
  __shared__ float vall[3*CP];

  int idx = (b << 9) + tid;
  int tok = sentence[idx];
  float al = alpha[idx];
  toksh[tid] = tok;
  float et  = EtT[(size_t)tok*128 + b];
  float4 eg = *(const float4*)(ETS + (size_t)tok*8);   // g0,g1,g2,ebs
  float e2v = ETS[(size_t)tok*8 + 4];
  float bst = EtT[(size_t)NV*128 + b];
  float4 brs = *(const float4*)(ETS + (size_t)NV*8);   // bsg0,bsg1,bsg2,bs2

  float sq  = al*al*e2v + 2.f*al*eg.w + brs.w;
  float ssv = (sq/(1.f+sq))/sqrtf(sq + SQ_EPS);
  float scv = (tok != 0) ? ssv*(al*et + bst) : MASK_NEG;
  float u0 = ssv*(al*eg.x + brs.x);
  float u1 = ssv*(al*eg.y + brs.y);
  float u2 = ssv*(al*eg.z + brs.z);

  float m = bmax512(scv, red, tid);
  float e = expf(scv - m);
  float Z = bsum512(e, red, tid);
  float nw = e / Z;
  float mk = fmaxf(u0, fmaxf(u1, u2));
  float e0 = expf(u0-mk), e1 = expf(u1-mk), e2 = expf(u2-mk);
  float wf = nw * scale_p[0] / (e0+e1+e2);
  float w0 = e0*wf, w1 = e1*wf, w2 = e2*wf;
  float ca = ssv * al;
  cfs[tid*3+0] = w0*ca; cfs[tid*3+1] = w1*ca; cfs[tid*3+2] = w2*ca;
  float sb0 = bsum512(w0*ssv, red, tid);
  float sb1 = bsum512(w1*ssv, red, tid);
  float sb2 = bsum512(w2*ssv, red, tid);
  __syncthreads();

  f32x4 A0 = {0.f,0.f,0.f,0.f}, A1 = A0, A2 = A0, R0 = A0, R1 = A0, R2 = A0;
  int c0 = lane << 2;
  int c1 = 256 + (lane << 2);
  bool rem = lane < 12;
  int base = w << 6;
  #pragma unroll 4
  for (int i = 0; i < 64; i++){
    int s = base + i;
    int t = toksh[s];
    const unsigned short* erow = E + (size_t)t*EP;
    uint2 ev = *(const uint2*)(erow + c0);
    float cf0 = cfs[s*3+0], cf1 = cfs[s*3+1], cf2 = cfs[s*3+2];
    f32x4 y;
    y[0] = bf2f((unsigned short)(ev.x & 0xffffu));
    y[1] = bf2f((unsigned short)(ev.x >> 16));
    y[2] = bf2f((unsigned short)(ev.y & 0xffffu));
    y[3] = bf2f((unsigned short)(ev.y >> 16));
    A0 += cf0*y; A1 += cf1*y; A2 += cf2*y;
    if (rem){
      uint2 ev2 = *(const uint2*)(erow + c1);
      f32x4 yr;
      yr[0] = bf2f((unsigned short)(ev2.x & 0xffffu));
      yr[1] = bf2f((unsigned short)(ev2.x >> 16));
      yr[2] = bf2f((unsigned short)(ev2.y & 0xffffu));
      yr[3] = bf2f((unsigned short)(ev2.y >> 16));
      R0 += cf0*yr; R1 += cf1*yr; R2 += cf2*yr;
    }
  }
  *(f32x4*)&cap8[w][0][c0] = A0;
  *(f32x4*)&cap8[w][1][c0] = A1;
  *(f32x4*)&cap8[w][2][c0] = A2;
  if (rem){
    *(f32x4*)&cap8[w][0][c1] = R0;
    *(f32x4*)&cap8[w][1][c1] = R1;
    *(f32x4*)&cap8[w][2][c1] = R2;
  }
  __syncthreads();
  float sbk[3] = {sb0, sb1, sb2};
  for (int p = tid; p < 3*CP; p += 512){
    int k = p / CP, c = p - k*CP;
    float v = sbk[k]*bsp[c];
    #pragma unroll
    for (int w8 = 0; w8 < 8; w8++) v += cap8[w8][k][c];
    vall[p] = v;
  }
  __syncthreads();
  #pragma unroll
  for (int k = 0; k < 3; k++){
    float x = 0.f;
    if (tid < CP){ float t = vall[k*CP + tid]; x = t*t; }
    float s = bsum512(x, red, tid);
    if (tid == 0){
      out[b*3 + k] = (s/(1.f+s))*sqrtf(s)/sqrtf(s + SQ_EPS);
    }
  }
}

extern "C" void kernel_launch(void* const* d_in, const int* in_sizes, int n_in,
                              void* d_out, int out_size, void* d_ws, size_t ws_size,
                              hipStream_t stream)
{
  (void)in_sizes; (void)n_in; (void)out_size; (void)ws_size;
  const int*   sentence = (const int*)d_in[0];
  const int*   aspect   = (const int*)d_in[1];
  const float* alpha    = (const float*)d_in[2];
  const float* embed    = (const float*)d_in[3];
  const float* Ws       = (const float*)d_in[4];
  const float* bs       = (const float*)d_in[5];
  const float* Wa       = (const float*)d_in[6];
  const float* ba       = (const float*)d_in[7];
  const float* Watt     = (const float*)d_in[8];
  const float* gcap     = (const float*)d_in[9];
  const float* gw       = (const float*)d_in[10];
  const float* scale    = (const float*)d_in[11];
  float* out = (float*)d_out;

  char* w = (char*)d_ws;
  auto alloc = [&](size_t bytes)->char*{
    char* p = w; w += (bytes + 255) & ~(size_t)255; return p;
  };
  unsigned short* WT  = (unsigned short*)alloc((size_t)KP*KP*2);
  unsigned short* E   = (unsigned short*)alloc((size_t)NV*EP*2);
  float* ETT = (float*)alloc((size_t)(NV+1)*128*4);
  float* ETS = (float*)alloc((size_t)(NV+1)*8*4);
  float* BSP = (float*)alloc(320*4);
  unsigned short* BMT = (unsigned short*)alloc((size_t)160*KP*2);

  kprep<<<157, 512, 0, stream>>>(Ws, Watt, gw, bs, gcap, aspect, embed, Wa, ba,
                                 WT, BSP, BMT);
  k1f<<<(NV + BM - 1)/BM + 1, 512, 0, stream>>>(embed, WT, BMT, BSP, E, ETT, ETS);
  k45<<<NB, 512, 0, stream>>>(sentence, alpha, scale, E, ETT, ETS, BSP, out);
}